// Round 3
// baseline (698.640 us; speedup 1.0000x reference)
//
#include <hip/hip_runtime.h>
#include <math.h>

#define B 8
#define S 2048
#define KIN 512
#define NIN 2048
#define NP 4096
#define HID 4096
#define DM 1024
#define TOPK 256

typedef __bf16 bf16x8 __attribute__((ext_vector_type(8)));
typedef __bf16 bf16x4 __attribute__((ext_vector_type(4)));
typedef float f32x4 __attribute__((ext_vector_type(4)));

__device__ __forceinline__ float gelu_exact(float x) {
    return 0.5f * x * (1.0f + erff(x * 0.70710678118654752440f));
}

__device__ __forceinline__ void atomicMaxFloat(float* addr, float val) {
    if (val >= 0.0f) atomicMax((int*)addr, __float_as_int(val));
    else             atomicMin((unsigned int*)addr, __float_as_uint(val));
}

// async 16B/lane global->LDS; lds base must be wave-uniform, lane l lands at base + l*16
__device__ __forceinline__ void async_copy16(void* lds, const void* g) {
    __builtin_amdgcn_global_load_lds(
        (__attribute__((address_space(1))) void*)g,
        (__attribute__((address_space(3))) void*)lds, 16, 0, 0);
}

__global__ __launch_bounds__(256) void init_kernel(float* scores, float* relacc,
                                                   float* hacc, unsigned* maskb,
                                                   int* selcnt) {
    int t = blockIdx.x * blockDim.x + threadIdx.x;
    if (t < B * NP)  { scores[t] = __int_as_float(0xFF800000); relacc[t] = 0.f; }
    if (t < B * HID) hacc[t] = 0.f;
    if (t < NIN)     maskb[t] = 0u;
    if (t < B)       selcnt[t] = 0;
}

__global__ __launch_bounds__(256) void scatter_maskbits(const int* __restrict__ idx,
                                                        unsigned* __restrict__ maskb) {
    int t = blockIdx.x * blockDim.x + threadIdx.x;
    if (t >= B * KIN) return;
    int b = t / KIN;
    atomicOr(&maskb[idx[t]], 1u << b);
}

// A fp32 [B][S][512] -> Apack bf16 [B][S][1024] = {hi(512) | lo(512)}
__global__ __launch_bounds__(256) void pack_A(const float* __restrict__ A,
                                              __bf16* __restrict__ Apack) {
    size_t t = (size_t)blockIdx.x * 256 + threadIdx.x;  // float4 index
    size_t f = t * 4;
    size_t rowi = f >> 9;
    int j = (int)(f & 511);
    float4 v = *(const float4*)(A + f);
    __bf16 h0 = (__bf16)v.x, h1 = (__bf16)v.y, h2 = (__bf16)v.z, h3 = (__bf16)v.w;
    bf16x4 hv = {h0, h1, h2, h3};
    bf16x4 lv = {(__bf16)(v.x - (float)h0), (__bf16)(v.y - (float)h1),
                 (__bf16)(v.z - (float)h2), (__bf16)(v.w - (float)h3)};
    __bf16* orow = Apack + rowi * 1024;
    *(bf16x4*)(orow + j) = hv;
    *(bf16x4*)(orow + 512 + j) = lv;
}

// One pass over cw: each block owns 4 cw rows in LDS, gathers for all 8 batches.
__global__ __launch_bounds__(256) void gather_pack_w(const float* __restrict__ cw,
                                                     const int* __restrict__ idx,
                                                     __bf16* __restrict__ wpack) {
    __shared__ float rowbuf[4][NIN];   // 32 KB
    __shared__ int sidx[B][KIN];       // 16 KB
    int p0 = blockIdx.x * 4;
    int tid = threadIdx.x;
    for (int t = tid; t < B * KIN; t += 256) sidx[t >> 9][t & 511] = idx[t];
#pragma unroll
    for (int r = 0; r < 4; ++r)
        for (int c = tid; c < NIN / 4; c += 256)
            *(float4*)&rowbuf[r][c * 4] = *(const float4*)&cw[(size_t)(p0 + r) * NIN + c * 4];
    __syncthreads();
#pragma unroll
    for (int r = 0; r < 4; ++r) {
        int p = p0 + r;
        for (int b = 0; b < B; ++b) {
            __bf16* orow = wpack + ((size_t)b * NP + p) * 1024;
            for (int j = tid; j < KIN; j += 256) {
                float x = rowbuf[r][sidx[b][j]];
                __bf16 hh = (__bf16)x;
                orow[j] = hh;
                orow[512 + j] = (__bf16)(x - (float)hh);
            }
        }
    }
}

// ---------------- 128x128 MFMA GEMM (kept for the two small GEMMs) ----------------
// EPI: 1 = gelu -> bf16 out ; 2 = raw fp32 out
template <int EPI, int NSEG, int KSEG, int LDA, int LDB, int BROWS, int LDOUT>
__global__ __launch_bounds__(256) void mfma_gemm(const __bf16* __restrict__ Ap,
                                                 const __bf16* __restrict__ Bp,
                                                 void* __restrict__ outp) {
    __shared__ __align__(16) __bf16 As[128 * 64];
    __shared__ __align__(16) __bf16 Ws[128 * 64];
    const int b = blockIdx.z;
    const int s0 = blockIdx.x * 128;
    const int p0 = blockIdx.y * 128;
    const int tid = threadIdx.x;
    const int w = tid >> 6, lane = tid & 63;
    const int wr = w >> 1, wc = w & 1;
    const int ldRow = lane >> 3;
    const int ldCol = ((lane & 7) ^ (ldRow & 7)) * 8;
    const int fr = lane & 15;
    const int fq = lane >> 4;
    const __bf16* Ab = Ap + ((size_t)b * S + s0) * LDA;
    const __bf16* Bb = Bp + ((size_t)b * BROWS + p0) * LDB;

    f32x4 acc[4][4] = {};

    for (int seg = 0; seg < NSEG; ++seg) {
        const int aoff = (seg == 1) ? KSEG : 0;
        const int boff = (seg == 2) ? KSEG : 0;
        for (int k0 = 0; k0 < KSEG; k0 += 64) {
            __syncthreads();
#pragma unroll
            for (int i = 0; i < 4; ++i) {
                const __bf16* g = Ab + (size_t)(w * 32 + i * 8 + ldRow) * LDA + aoff + k0 + ldCol;
                async_copy16(&As[(w * 32 + i * 8) * 64], g);
            }
#pragma unroll
            for (int i = 0; i < 4; ++i) {
                const __bf16* g = Bb + (size_t)(w * 32 + i * 8 + ldRow) * LDB + boff + k0 + ldCol;
                async_copy16(&Ws[(w * 32 + i * 8) * 64], g);
            }
            __syncthreads();
#pragma unroll
            for (int ks = 0; ks < 2; ++ks) {
                bf16x8 af[4], bfr[4];
#pragma unroll
                for (int i = 0; i < 4; ++i) {
                    int R = wr * 64 + i * 16 + fr;
                    af[i] = *(const bf16x8*)&As[R * 64 + (((ks * 4 + fq) ^ (R & 7)) * 8)];
                }
#pragma unroll
                for (int j = 0; j < 4; ++j) {
                    int R = wc * 64 + j * 16 + fr;
                    bfr[j] = *(const bf16x8*)&Ws[R * 64 + (((ks * 4 + fq) ^ (R & 7)) * 8)];
                }
#pragma unroll
                for (int i = 0; i < 4; ++i)
#pragma unroll
                    for (int j = 0; j < 4; ++j)
                        acc[i][j] = __builtin_amdgcn_mfma_f32_16x16x32_bf16(af[i], bfr[j], acc[i][j], 0, 0, 0);
            }
        }
    }

    if constexpr (EPI == 1) {
        __bf16* o = (__bf16*)outp;
#pragma unroll
        for (int i = 0; i < 4; ++i)
#pragma unroll
            for (int r = 0; r < 4; ++r) {
                size_t row = (size_t)b * S + s0 + wr * 64 + i * 16 + fq * 4 + r;
#pragma unroll
                for (int j = 0; j < 4; ++j)
                    o[row * LDOUT + p0 + wc * 64 + j * 16 + fr] = (__bf16)gelu_exact(acc[i][j][r]);
            }
    } else {
        float* o = (float*)outp;
#pragma unroll
        for (int i = 0; i < 4; ++i)
#pragma unroll
            for (int r = 0; r < 4; ++r) {
                size_t row = (size_t)b * S + s0 + wr * 64 + i * 16 + fq * 4 + r;
#pragma unroll
                for (int j = 0; j < 4; ++j)
                    o[row * LDOUT + p0 + wc * 64 + j * 16 + fr] = acc[i][j][r];
            }
    }
}

// ---------------- 256x256 8-wave pipelined MFMA GEMM (scores GEMM) ----------------
// One-barrier-per-phase read-ahead schedule. 4 phases/K-tile: A(m0,k0) B(m1,k0)
// C(m0,k1) D(m1,k1). Fragment reads for phase p issue at end of phase p-1, so
// lgkmcnt(0) at phase start waits on phase-old reads (latency hidden) and the
// LDS unit overlaps the MFMA pipe. Staging: A stages rows{64,192} of t+1 into
// buf[nxt]; D stages rows{0,128} of t+2 into buf[cur]. vmcnt(0) at C drains all
// t+1 stages BEFORE D's barrier, making the end-of-D reads of buf[nxt] safe
// cross-wave (per-wave vmcnt + intervening barrier). Stage-overwrite safety:
// each staged region's last reader lgkm'd >=1 barrier before the stage issue.
__device__ __forceinline__ void stage64(__bf16* ldsTile, const __bf16* gRow0,
                                        int rbase, int ldg, int koff, int w, int lane) {
    const int rr = lane >> 3;                 // 0..7 rows per wave per issue
    const int gc = ((lane & 7) ^ rr) * 8;     // pre-swizzled global chunk
    const __bf16* g = gRow0 + (size_t)(rbase + w * 8 + rr) * ldg + (koff + gc);
    async_copy16(ldsTile + (rbase + w * 8) * 64, g);  // wave-uniform LDS base
}

template <int EPI, int NSEG, int KSEG, int LDA, int LDB, int BROWS, int LDOUT>
__global__ __launch_bounds__(512, 2) void mfma_gemm256(const __bf16* __restrict__ Ap,
                                                       const __bf16* __restrict__ Bp,
                                                       void* __restrict__ outp) {
    constexpr int TPS = KSEG / 64;
    constexpr int NT = NSEG * TPS;
    __shared__ __align__(16) __bf16 As[2][256 * 64];  // 2 x 32 KB
    __shared__ __align__(16) __bf16 Ws[2][256 * 64];  // 2 x 32 KB

    // XCD-aware remap (grid fixed at (8,16,8); dispatch order x-fastest, XCD = flat%8)
    const int flat = blockIdx.x + (blockIdx.y << 3) + (blockIdx.z << 7);
    const int b = flat & 7;                 // batch == XCD
    const int j = flat >> 3;                // 0..127 within XCD
    const int s0 = (j & 7) * 256;           // S tile (inner: concurrent blocks share A)
    const int p0 = (j >> 3) * 256;          // NP tile

    const int tid = threadIdx.x;
    const int w = tid >> 6, lane = tid & 63;
    const int wr = w >> 2, wc = w & 3;        // 2 x 4 wave grid, each owns 128x64
    const int fr = lane & 15, fq = lane >> 4;
    const __bf16* Ab = Ap + ((size_t)b * S + s0) * LDA;
    const __bf16* Bb = Bp + ((size_t)b * BROWS + p0) * LDB;

    auto offs = [&](int t, int& ao, int& bo) {
        int seg = t / TPS, k0 = (t % TPS) * 64;
        ao = ((NSEG == 3 && seg == 1) ? KSEG : 0) + k0;
        bo = ((NSEG == 3 && seg == 2) ? KSEG : 0) + k0;
    };

    // Hoisted LDS-read offsets (loop-invariant; static indexing only -> registers)
    int offA[2][2][4];  // [kk][mh][mi]
    int offB[2][4];     // [kk][nj]
#pragma unroll
    for (int kk = 0; kk < 2; ++kk) {
#pragma unroll
        for (int mh = 0; mh < 2; ++mh)
#pragma unroll
            for (int mi = 0; mi < 4; ++mi) {
                int R = wr * 128 + mh * 64 + mi * 16 + fr;
                offA[kk][mh][mi] = R * 64 + (((kk * 4 + fq) ^ (R & 7)) * 8);
            }
#pragma unroll
        for (int nj = 0; nj < 4; ++nj) {
            int R = wc * 64 + nj * 16 + fr;
            offB[kk][nj] = R * 64 + (((kk * 4 + fq) ^ (R & 7)) * 8);
        }
    }

    bf16x8 rA0[4], rA1[4], rB0[4], rB1[4];
    f32x4 acc[8][4] = {};

    auto RDA = [&](bf16x8* dst, const __bf16* base, int mh, int kk) {
#pragma unroll
        for (int i = 0; i < 4; ++i) dst[i] = *(const bf16x8*)&base[offA[kk][mh][i]];
    };
    auto RDB = [&](bf16x8* dst, const __bf16* base, int kk) {
#pragma unroll
        for (int n = 0; n < 4; ++n) dst[n] = *(const bf16x8*)&base[offB[kk][n]];
    };
    auto MMA = [&](int q, const bf16x8* a, const bf16x8* bf) {
#pragma unroll
        for (int mi = 0; mi < 4; ++mi)
#pragma unroll
            for (int nj = 0; nj < 4; ++nj)
                acc[q + mi][nj] = __builtin_amdgcn_mfma_f32_16x16x32_bf16(a[mi], bf[nj], acc[q + mi][nj], 0, 0, 0);
    };

    {   // prologue: tile0 full (8 issues) + tile1 rows{0,128} (4 issues)
        int ao, bo;
        offs(0, ao, bo);
        stage64(&As[0][0], Ab, 0, LDA, ao, w, lane);
        stage64(&As[0][0], Ab, 128, LDA, ao, w, lane);
        stage64(&As[0][0], Ab, 64, LDA, ao, w, lane);
        stage64(&As[0][0], Ab, 192, LDA, ao, w, lane);
        stage64(&Ws[0][0], Bb, 0, LDB, bo, w, lane);
        stage64(&Ws[0][0], Bb, 128, LDB, bo, w, lane);
        stage64(&Ws[0][0], Bb, 64, LDB, bo, w, lane);
        stage64(&Ws[0][0], Bb, 192, LDB, bo, w, lane);
        if (NT > 1) {
            offs(1, ao, bo);
            stage64(&As[1][0], Ab, 0, LDA, ao, w, lane);
            stage64(&As[1][0], Ab, 128, LDA, ao, w, lane);
            stage64(&Ws[1][0], Bb, 0, LDB, bo, w, lane);
            stage64(&Ws[1][0], Bb, 128, LDB, bo, w, lane);
            asm volatile("s_waitcnt vmcnt(4)" ::: "memory");
        } else {
            asm volatile("s_waitcnt vmcnt(0)" ::: "memory");
        }
        __builtin_amdgcn_s_barrier();   // all waves' tile0 stages landed
        RDA(rA0, &As[0][0], 0, 0);      // phase-A reads, one phase early
        RDB(rB0, &Ws[0][0], 0);
    }

    for (int t = 0; t < NT; ++t) {
        const int cur = t & 1, nxt = cur ^ 1;
        const __bf16* Asb = &As[cur][0];
        const __bf16* Wsb = &Ws[cur][0];

        // ---- Phase A: m0,kk0 ; stage rows{64,192} of t+1 -> buf[nxt] ----
        __builtin_amdgcn_s_barrier();
        asm volatile("s_waitcnt lgkmcnt(0)" ::: "memory");
        __builtin_amdgcn_sched_barrier(0);
        __builtin_amdgcn_s_setprio(1);
        MMA(0, rA0, rB0);
        __builtin_amdgcn_s_setprio(0);
        __builtin_amdgcn_sched_barrier(0);
        if (t + 1 < NT) {
            int ao, bo;
            offs(t + 1, ao, bo);
            stage64(&As[nxt][0], Ab, 64, LDA, ao, w, lane);
            stage64(&As[nxt][0], Ab, 192, LDA, ao, w, lane);
            stage64(&Ws[nxt][0], Bb, 64, LDB, bo, w, lane);
            stage64(&Ws[nxt][0], Bb, 192, LDB, bo, w, lane);
        }
        RDA(rA1, Asb, 1, 0);

        // ---- Phase B: m1,kk0 ----
        __builtin_amdgcn_s_barrier();
        asm volatile("s_waitcnt lgkmcnt(0)" ::: "memory");
        __builtin_amdgcn_sched_barrier(0);
        __builtin_amdgcn_s_setprio(1);
        MMA(4, rA1, rB0);
        __builtin_amdgcn_s_setprio(0);
        __builtin_amdgcn_sched_barrier(0);
        RDA(rA0, Asb, 0, 1);
        RDB(rB1, Wsb, 1);

        // ---- Phase C: m0,kk1 ; drain ALL t+1 stages (before D's barrier) ----
        __builtin_amdgcn_s_barrier();
        asm volatile("s_waitcnt lgkmcnt(0)" ::: "memory");
        __builtin_amdgcn_sched_barrier(0);
        __builtin_amdgcn_s_setprio(1);
        MMA(0, rA0, rB1);
        __builtin_amdgcn_s_setprio(0);
        __builtin_amdgcn_sched_barrier(0);
        asm volatile("s_waitcnt vmcnt(0)" ::: "memory");
        __builtin_amdgcn_sched_barrier(0);
        RDA(rA1, Asb, 1, 1);

        // ---- Phase D: m1,kk1 ; stage rows{0,128} of t+2 -> buf[cur] ; read t+1 ----
        __builtin_amdgcn_s_barrier();
        asm volatile("s_waitcnt lgkmcnt(0)" ::: "memory");
        __builtin_amdgcn_sched_barrier(0);
        __builtin_amdgcn_s_setprio(1);
        MMA(4, rA1, rB1);
        __builtin_amdgcn_s_setprio(0);
        __builtin_amdgcn_sched_barrier(0);
        if (t + 2 < NT) {
            int ao, bo;
            offs(t + 2, ao, bo);
            stage64(&As[cur][0], Ab, 0, LDA, ao, w, lane);
            stage64(&As[cur][0], Ab, 128, LDA, ao, w, lane);
            stage64(&Ws[cur][0], Bb, 0, LDB, bo, w, lane);
            stage64(&Ws[cur][0], Bb, 128, LDB, bo, w, lane);
        }
        if (t + 1 < NT) {   // reads of buf[nxt]: safe (vmcnt@C + D's barrier)
            RDA(rA0, &As[nxt][0], 0, 0);
            RDB(rB0, &Ws[nxt][0], 0);
        }
    }

    // C/D layout: col = fr, row = fq*4 + reg  [m89/m91 verified]
    if constexpr (EPI == 0) {
        // gelu is quasiconvex (min at x~-0.75): max_s gelu(x) = max(gelu(min x), gelu(max x))
        float* scores = (float*)outp;
#pragma unroll
        for (int nj = 0; nj < 4; ++nj) {
            float mx = -INFINITY, mn = INFINITY;
#pragma unroll
            for (int mi = 0; mi < 8; ++mi)
#pragma unroll
                for (int r = 0; r < 4; ++r) {
                    float v = acc[mi][nj][r];
                    mx = fmaxf(mx, v);
                    mn = fminf(mn, v);
                }
            mx = fmaxf(mx, __shfl_xor(mx, 16));
            mx = fmaxf(mx, __shfl_xor(mx, 32));
            mn = fminf(mn, __shfl_xor(mn, 16));
            mn = fminf(mn, __shfl_xor(mn, 32));
            if (fq == 0) {
                float m = fmaxf(gelu_exact(mx), gelu_exact(mn));
                atomicMaxFloat(&scores[(size_t)b * LDOUT + p0 + wc * 64 + nj * 16 + fr], m);
            }
        }
    } else if constexpr (EPI == 1) {
        __bf16* o = (__bf16*)outp;
#pragma unroll
        for (int mi = 0; mi < 8; ++mi)
#pragma unroll
            for (int r = 0; r < 4; ++r) {
                size_t row = (size_t)b * S + s0 + wr * 128 + mi * 16 + fq * 4 + r;
#pragma unroll
                for (int nj = 0; nj < 4; ++nj)
                    o[row * LDOUT + p0 + wc * 64 + nj * 16 + fr] = (__bf16)gelu_exact(acc[mi][nj][r]);
            }
    } else {
        float* o = (float*)outp;
#pragma unroll
        for (int mi = 0; mi < 8; ++mi)
#pragma unroll
            for (int r = 0; r < 4; ++r) {
                size_t row = (size_t)b * S + s0 + wr * 128 + mi * 16 + fq * 4 + r;
#pragma unroll
                for (int nj = 0; nj < 4; ++nj)
                    o[row * LDOUT + p0 + wc * 64 + nj * 16 + fr] = acc[mi][nj][r];
            }
    }
}

// ---- MLP: read w1/w2 exactly once, loop batches in-register, partial-sum atomics ----
__global__ __launch_bounds__(256) void mlp1_part(const float* __restrict__ w1,
                                                 const unsigned* __restrict__ maskb,
                                                 float* __restrict__ hacc) {
    __shared__ unsigned smb[512];
    int i0 = blockIdx.x * 64;
    int c0 = blockIdx.y * 512;
    int tid = threadIdx.x;
    for (int c = tid; c < 512; c += 256) smb[c] = maskb[c0 + c];
    __syncthreads();
    int r = tid >> 2, cq = tid & 3;
    const float* row = w1 + (size_t)(i0 + r) * NIN + c0;
    float acc[B] = {};
    for (int it = 0; it < 32; ++it) {
        int c = it * 16 + cq * 4;
        float4 v = *(const float4*)(row + c);
        float vv[4] = {v.x, v.y, v.z, v.w};
#pragma unroll
        for (int e = 0; e < 4; ++e) {
            unsigned mb = smb[c + e];
#pragma unroll
            for (int bb = 0; bb < B; ++bb)
                if (mb & (1u << bb)) acc[bb] += vv[e];
        }
    }
#pragma unroll
    for (int bb = 0; bb < B; ++bb)
        atomicAdd(&hacc[bb * HID + i0 + r], acc[bb]);
}

__global__ __launch_bounds__(256) void fin1(const float* __restrict__ hacc,
                                            const float* __restrict__ b1,
                                            float* __restrict__ h) {
    int t = blockIdx.x * 256 + threadIdx.x;
    if (t < B * HID) h[t] = gelu_exact(hacc[t] + b1[t & (HID - 1)]);
}

__global__ __launch_bounds__(256) void mlp2_part(const float* __restrict__ w2,
                                                 const float* __restrict__ h,
                                                 float* __restrict__ relacc) {
    __shared__ float sh[B][512];
    int p0 = blockIdx.x * 64;
    int c0 = blockIdx.y * 512;
    int tid = threadIdx.x;
    for (int i = tid; i < B * 128; i += 256) {
        int bb = i >> 7, c4 = i & 127;
        *(float4*)&sh[bb][c4 * 4] = *(const float4*)&h[(size_t)bb * HID + c0 + c4 * 4];
    }
    __syncthreads();
    int r = tid >> 2, cq = tid & 3;
    const float* row = w2 + (size_t)(p0 + r) * HID + c0;
    float acc[B] = {};
    for (int it = 0; it < 32; ++it) {
        int c = it * 16 + cq * 4;
        float4 v = *(const float4*)(row + c);
#pragma unroll
        for (int bb = 0; bb < B; ++bb)
            acc[bb] += v.x * sh[bb][c] + v.y * sh[bb][c + 1] + v.z * sh[bb][c + 2] + v.w * sh[bb][c + 3];
    }
#pragma unroll
    for (int bb = 0; bb < B; ++bb)
        atomicAdd(&relacc[bb * NP + p0 + r], acc[bb]);
}

// Exact top-k set via rank counting, jax.lax.top_k tie-break (lower index wins).
// fin2 (sigmoid gating) fused into the LDS fill: identical float math in every
// block -> consistent sc[] across blocks.
__global__ __launch_bounds__(256) void topk_select(const float* __restrict__ scores,
                                                   const float* __restrict__ relacc,
                                                   const float* __restrict__ b2,
                                                   int* __restrict__ selidx,
                                                   int* __restrict__ selcnt) {
    __shared__ float sc[NP];
    int b = blockIdx.y;
    int p = blockIdx.x * 256 + threadIdx.x;
    for (int c = threadIdx.x; c < NP; c += 256) {
        float rel = relacc[(size_t)b * NP + c] + b2[c];
        sc[c] = scores[(size_t)b * NP + c] * (1.0f / (1.0f + expf(-rel)));
    }
    __syncthreads();
    float my = sc[p];
    int cnt = 0;
    for (int q = 0; q < NP; ++q) {
        float v = sc[q];
        cnt += (v > my) || (v == my && q < p);
    }
    if (cnt < TOPK) {
        int pos = atomicAdd(&selcnt[b], 1);
        selidx[b * TOPK + pos] = p;  // order arbitrary; final einsum is a sum
    }
}

// Wsel[b][kk][0:512] = Wpack[b][sel[kk]][0:512]  (hi half only)
__global__ __launch_bounds__(256) void wsel_gather(const __bf16* __restrict__ wpack,
                                                   const int* __restrict__ selidx,
                                                   __bf16* __restrict__ wsel) {
    int kk = blockIdx.x, b = blockIdx.y;
    int sel = selidx[b * TOPK + kk];
    const unsigned* src = (const unsigned*)(wpack + ((size_t)b * NP + sel) * 1024);
    unsigned* dst = (unsigned*)(wsel + ((size_t)b * TOPK + kk) * 512);
    dst[threadIdx.x] = src[threadIdx.x];  // 256 uints = 512 bf16
}

// PT[b][d][kk] = bf16(proj[sel[kk]][d])  via LDS transpose
__global__ __launch_bounds__(256) void projT_gather(const float* __restrict__ proj,
                                                    const int* __restrict__ selidx,
                                                    __bf16* __restrict__ PT) {
    __shared__ float tile[64][68];
    __shared__ int sel[64];
    int b = blockIdx.z, d0 = blockIdx.x * 64, k0 = blockIdx.y * 64;
    int tid = threadIdx.x;
    if (tid < 64) sel[tid] = selidx[b * TOPK + k0 + tid];
    __syncthreads();
    for (int r = 0; r < 4; ++r) {
        int kk = r * 16 + (tid >> 4);
        float4 v = *(const float4*)&proj[(size_t)sel[kk] * DM + d0 + (tid & 15) * 4];
        *(float4*)&tile[kk][(tid & 15) * 4] = v;
    }
    __syncthreads();
    for (int r = 0; r < 16; ++r) {
        int dd = r * 4 + (tid >> 6);
        int kk = tid & 63;
        PT[((size_t)b * DM + d0 + dd) * TOPK + k0 + kk] = (__bf16)tile[kk][dd];
    }
}

extern "C" void kernel_launch(void* const* d_in, const int* in_sizes, int n_in,
                              void* d_out, int out_size, void* d_ws, size_t ws_size,
                              hipStream_t stream) {
    const float* A    = (const float*)d_in[0];
    const int*   idx  = (const int*)d_in[1];
    const float* cw   = (const float*)d_in[3];
    const float* proj = (const float*)d_in[4];
    const float* w1   = (const float*)d_in[5];
    const float* b1   = (const float*)d_in[6];
    const float* w2   = (const float*)d_in[7];
    const float* b2   = (const float*)d_in[8];
    float* out = (float*)d_out;

    char* ws = (char*)d_ws;
    size_t off = 0;
    auto alloc = [&](size_t bytes) {
        void* p = ws + off;
        off += (bytes + 255) & ~(size_t)255;
        return p;
    };
    __bf16* Apack = (__bf16*)alloc((size_t)B * S * 1024 * 2);    // 33.5 MB
    __bf16* Wpack = (__bf16*)alloc((size_t)B * NP * 1024 * 2);   // 67 MB
    __bf16* selpa = (__bf16*)alloc((size_t)B * S * TOPK * 2);    // 8.4 MB
    __bf16* PT    = (__bf16*)alloc((size_t)B * DM * TOPK * 2);   // 4.2 MB
    __bf16* Wsel  = (__bf16*)alloc((size_t)B * TOPK * 512 * 2);  // 2.1 MB
    float* scores = (float*)alloc((size_t)B * NP * 4);
    float* relacc = (float*)alloc((size_t)B * NP * 4);
    float* hacc   = (float*)alloc((size_t)B * HID * 4);
    float* h      = (float*)alloc((size_t)B * HID * 4);
    unsigned* maskb = (unsigned*)alloc((size_t)NIN * 4);
    int* selidx   = (int*)alloc((size_t)B * TOPK * 4);
    int* selcnt   = (int*)alloc((size_t)B * 4);

    init_kernel<<<dim3((B * HID + 255) / 256), 256, 0, stream>>>(scores, relacc, hacc, maskb, selcnt);
    scatter_maskbits<<<dim3((B * KIN + 255) / 256), 256, 0, stream>>>(idx, maskb);
    pack_A<<<dim3((B * S * KIN / 4) / 256), 256, 0, stream>>>(A, Apack);
    gather_pack_w<<<dim3(NP / 4), 256, 0, stream>>>(cw, idx, Wpack);

    // scores: split-fp32 (3 segments) bf16 MFMA, 256^2 one-barrier pipeline +
    // XCD remap, fused max+gelu epilogue
    mfma_gemm256<0, 3, 512, 1024, 1024, NP, NP>
        <<<dim3(S / 256, NP / 256, B), 512, 0, stream>>>(Apack, Wpack, (void*)scores);

    mlp1_part<<<dim3(HID / 64, NIN / 512), 256, 0, stream>>>(w1, maskb, hacc);
    fin1<<<dim3((B * HID + 255) / 256), 256, 0, stream>>>(hacc, b1, h);
    mlp2_part<<<dim3(NP / 64, HID / 512), 256, 0, stream>>>(w2, h, relacc);

    topk_select<<<dim3(NP / 256, B), 256, 0, stream>>>(scores, relacc, b2, selidx, selcnt);

    wsel_gather<<<dim3(TOPK, B), 256, 0, stream>>>(Wpack, selidx, Wsel);
    projT_gather<<<dim3(DM / 64, TOPK / 64, B), 256, 0, stream>>>(proj, selidx, PT);

    // selpa = gelu(A * Wsel^T) in bf16 (hi-only, 1 segment)
    mfma_gemm<1, 1, 512, 1024, 512, TOPK, TOPK>
        <<<dim3(S / 128, TOPK / 128, B), 256, 0, stream>>>(Apack, Wsel, (void*)selpa);

    // out = selpa * PT^T  (K=256, fp32 store)
    mfma_gemm<2, 1, 256, 256, 256, DM, DM>
        <<<dim3(S / 128, DM / 128, B), 256, 0, stream>>>(selpa, PT, (void*)out);
}

// Round 4
// 655.462 us; speedup vs baseline: 1.0659x; 1.0659x over previous
//
#include <hip/hip_runtime.h>
#include <math.h>

#define B 8
#define S 2048
#define KIN 512
#define NIN 2048
#define NP 4096
#define HID 4096
#define DM 1024
#define TOPK 256

typedef __bf16 bf16x8 __attribute__((ext_vector_type(8)));
typedef __bf16 bf16x4 __attribute__((ext_vector_type(4)));
typedef float f32x4 __attribute__((ext_vector_type(4)));

__device__ __forceinline__ float gelu_exact(float x) {
    return 0.5f * x * (1.0f + erff(x * 0.70710678118654752440f));
}

__device__ __forceinline__ void atomicMaxFloat(float* addr, float val) {
    if (val >= 0.0f) atomicMax((int*)addr, __float_as_int(val));
    else             atomicMin((unsigned int*)addr, __float_as_uint(val));
}

// async 16B/lane global->LDS; lds base must be wave-uniform, lane l lands at base + l*16
__device__ __forceinline__ void async_copy16(void* lds, const void* g) {
    __builtin_amdgcn_global_load_lds(
        (__attribute__((address_space(1))) void*)g,
        (__attribute__((address_space(3))) void*)lds, 16, 0, 0);
}

__global__ __launch_bounds__(256) void init_kernel(float* scores, float* relacc,
                                                   float* hacc, unsigned* maskb,
                                                   int* selcnt) {
    int t = blockIdx.x * blockDim.x + threadIdx.x;
    if (t < B * NP)  { scores[t] = __int_as_float(0xFF800000); relacc[t] = 0.f; }
    if (t < B * HID) hacc[t] = 0.f;
    if (t < NIN)     maskb[t] = 0u;
    if (t < B)       selcnt[t] = 0;
}

__global__ __launch_bounds__(256) void scatter_maskbits(const int* __restrict__ idx,
                                                        unsigned* __restrict__ maskb) {
    int t = blockIdx.x * blockDim.x + threadIdx.x;
    if (t >= B * KIN) return;
    int b = t / KIN;
    atomicOr(&maskb[idx[t]], 1u << b);
}

// A fp32 [B][S][512] -> Apack bf16 [B][S][1024] = {hi(512) | lo(512)}
__global__ __launch_bounds__(256) void pack_A(const float* __restrict__ A,
                                              __bf16* __restrict__ Apack) {
    size_t t = (size_t)blockIdx.x * 256 + threadIdx.x;  // float4 index
    size_t f = t * 4;
    size_t rowi = f >> 9;
    int j = (int)(f & 511);
    float4 v = *(const float4*)(A + f);
    __bf16 h0 = (__bf16)v.x, h1 = (__bf16)v.y, h2 = (__bf16)v.z, h3 = (__bf16)v.w;
    bf16x4 hv = {h0, h1, h2, h3};
    bf16x4 lv = {(__bf16)(v.x - (float)h0), (__bf16)(v.y - (float)h1),
                 (__bf16)(v.z - (float)h2), (__bf16)(v.w - (float)h3)};
    __bf16* orow = Apack + rowi * 1024;
    *(bf16x4*)(orow + j) = hv;
    *(bf16x4*)(orow + 512 + j) = lv;
}

// One pass over cw: each block owns 4 cw rows in LDS, gathers for all 8 batches.
__global__ __launch_bounds__(256) void gather_pack_w(const float* __restrict__ cw,
                                                     const int* __restrict__ idx,
                                                     __bf16* __restrict__ wpack) {
    __shared__ float rowbuf[4][NIN];   // 32 KB
    __shared__ int sidx[B][KIN];       // 16 KB
    int p0 = blockIdx.x * 4;
    int tid = threadIdx.x;
    for (int t = tid; t < B * KIN; t += 256) sidx[t >> 9][t & 511] = idx[t];
#pragma unroll
    for (int r = 0; r < 4; ++r)
        for (int c = tid; c < NIN / 4; c += 256)
            *(float4*)&rowbuf[r][c * 4] = *(const float4*)&cw[(size_t)(p0 + r) * NIN + c * 4];
    __syncthreads();
#pragma unroll
    for (int r = 0; r < 4; ++r) {
        int p = p0 + r;
        for (int b = 0; b < B; ++b) {
            __bf16* orow = wpack + ((size_t)b * NP + p) * 1024;
            for (int j = tid; j < KIN; j += 256) {
                float x = rowbuf[r][sidx[b][j]];
                __bf16 hh = (__bf16)x;
                orow[j] = hh;
                orow[512 + j] = (__bf16)(x - (float)hh);
            }
        }
    }
}

// ---------------- 128x128 MFMA GEMM (kept for the two small GEMMs) ----------------
// EPI: 1 = gelu -> bf16 out ; 2 = raw fp32 out
template <int EPI, int NSEG, int KSEG, int LDA, int LDB, int BROWS, int LDOUT>
__global__ __launch_bounds__(256) void mfma_gemm(const __bf16* __restrict__ Ap,
                                                 const __bf16* __restrict__ Bp,
                                                 void* __restrict__ outp) {
    __shared__ __align__(16) __bf16 As[128 * 64];
    __shared__ __align__(16) __bf16 Ws[128 * 64];
    const int b = blockIdx.z;
    const int s0 = blockIdx.x * 128;
    const int p0 = blockIdx.y * 128;
    const int tid = threadIdx.x;
    const int w = tid >> 6, lane = tid & 63;
    const int wr = w >> 1, wc = w & 1;
    const int ldRow = lane >> 3;
    const int ldCol = ((lane & 7) ^ (ldRow & 7)) * 8;
    const int fr = lane & 15;
    const int fq = lane >> 4;
    const __bf16* Ab = Ap + ((size_t)b * S + s0) * LDA;
    const __bf16* Bb = Bp + ((size_t)b * BROWS + p0) * LDB;

    f32x4 acc[4][4] = {};

    for (int seg = 0; seg < NSEG; ++seg) {
        const int aoff = (seg == 1) ? KSEG : 0;
        const int boff = (seg == 2) ? KSEG : 0;
        for (int k0 = 0; k0 < KSEG; k0 += 64) {
            __syncthreads();
#pragma unroll
            for (int i = 0; i < 4; ++i) {
                const __bf16* g = Ab + (size_t)(w * 32 + i * 8 + ldRow) * LDA + aoff + k0 + ldCol;
                async_copy16(&As[(w * 32 + i * 8) * 64], g);
            }
#pragma unroll
            for (int i = 0; i < 4; ++i) {
                const __bf16* g = Bb + (size_t)(w * 32 + i * 8 + ldRow) * LDB + boff + k0 + ldCol;
                async_copy16(&Ws[(w * 32 + i * 8) * 64], g);
            }
            __syncthreads();
#pragma unroll
            for (int ks = 0; ks < 2; ++ks) {
                bf16x8 af[4], bfr[4];
#pragma unroll
                for (int i = 0; i < 4; ++i) {
                    int R = wr * 64 + i * 16 + fr;
                    af[i] = *(const bf16x8*)&As[R * 64 + (((ks * 4 + fq) ^ (R & 7)) * 8)];
                }
#pragma unroll
                for (int j = 0; j < 4; ++j) {
                    int R = wc * 64 + j * 16 + fr;
                    bfr[j] = *(const bf16x8*)&Ws[R * 64 + (((ks * 4 + fq) ^ (R & 7)) * 8)];
                }
#pragma unroll
                for (int i = 0; i < 4; ++i)
#pragma unroll
                    for (int j = 0; j < 4; ++j)
                        acc[i][j] = __builtin_amdgcn_mfma_f32_16x16x32_bf16(af[i], bfr[j], acc[i][j], 0, 0, 0);
            }
        }
    }

    if constexpr (EPI == 1) {
        __bf16* o = (__bf16*)outp;
#pragma unroll
        for (int i = 0; i < 4; ++i)
#pragma unroll
            for (int r = 0; r < 4; ++r) {
                size_t row = (size_t)b * S + s0 + wr * 64 + i * 16 + fq * 4 + r;
#pragma unroll
                for (int j = 0; j < 4; ++j)
                    o[row * LDOUT + p0 + wc * 64 + j * 16 + fr] = (__bf16)gelu_exact(acc[i][j][r]);
            }
    } else {
        float* o = (float*)outp;
#pragma unroll
        for (int i = 0; i < 4; ++i)
#pragma unroll
            for (int r = 0; r < 4; ++r) {
                size_t row = (size_t)b * S + s0 + wr * 64 + i * 16 + fq * 4 + r;
#pragma unroll
                for (int j = 0; j < 4; ++j)
                    o[row * LDOUT + p0 + wc * 64 + j * 16 + fr] = acc[i][j][r];
            }
    }
}

// ---------------- 256x256 8-wave pipelined MFMA GEMM (scores GEMM) ----------------
// R2 skeleton (two barriers/phase, stage at P1/P4, vmcnt(4) never 0, setprio,
// XCD remap). Change vs R2: NO blunt `s_waitcnt lgkmcnt(0)` before the MFMA
// clusters — fragment loads are intrinsic-level, so the compiler emits
// fine-grained per-use lgkmcnt(N) waits (m97 evidence): the first MFMA needs
// only its own 2 reads, so the remaining LDS burst drains UNDER the cluster
// instead of serializing ahead of it. Reads ordered af0,bfr0..3,af1..3 so the
// first MFMA's operands are reads #1-2. Cross-wave staging safety is carried
// by the vmcnt(4)+barrier protocol (unchanged), not lgkm.
__device__ __forceinline__ void stage64(__bf16* ldsTile, const __bf16* gRow0,
                                        int rbase, int ldg, int koff, int w, int lane) {
    const int rr = lane >> 3;                 // 0..7 rows per wave per issue
    const int gc = ((lane & 7) ^ rr) * 8;     // pre-swizzled global chunk
    const __bf16* g = gRow0 + (size_t)(rbase + w * 8 + rr) * ldg + (koff + gc);
    async_copy16(ldsTile + (rbase + w * 8) * 64, g);  // wave-uniform LDS base
}

template <int EPI, int NSEG, int KSEG, int LDA, int LDB, int BROWS, int LDOUT>
__global__ __launch_bounds__(512, 2) void mfma_gemm256(const __bf16* __restrict__ Ap,
                                                       const __bf16* __restrict__ Bp,
                                                       void* __restrict__ outp) {
    constexpr int TPS = KSEG / 64;
    constexpr int NT = NSEG * TPS;
    __shared__ __align__(16) __bf16 As[2][256 * 64];  // 2 x 32 KB
    __shared__ __align__(16) __bf16 Ws[2][256 * 64];  // 2 x 32 KB

    // XCD-aware remap (grid fixed at (8,16,8); dispatch order x-fastest, XCD = flat%8)
    const int flat = blockIdx.x + (blockIdx.y << 3) + (blockIdx.z << 7);
    const int b = flat & 7;                 // batch == XCD
    const int j = flat >> 3;                // 0..127 within XCD
    const int s0 = (j & 7) * 256;           // S tile (inner: concurrent blocks share A)
    const int p0 = (j >> 3) * 256;          // NP tile

    const int tid = threadIdx.x;
    const int w = tid >> 6, lane = tid & 63;
    const int wr = w >> 2, wc = w & 3;        // 2 x 4 wave grid, each owns 128x64
    const int fr = lane & 15, fq = lane >> 4;
    const __bf16* Ab = Ap + ((size_t)b * S + s0) * LDA;
    const __bf16* Bb = Bp + ((size_t)b * BROWS + p0) * LDB;

    auto offs = [&](int t, int& ao, int& bo) {
        int seg = t / TPS, k0 = (t % TPS) * 64;
        ao = ((NSEG == 3 && seg == 1) ? KSEG : 0) + k0;
        bo = ((NSEG == 3 && seg == 2) ? KSEG : 0) + k0;
    };

    // Hoisted LDS-read offsets (loop-invariant; static indexing only -> registers)
    int offA[2][2][4];  // [kk][mh][mi]
    int offB[2][4];     // [kk][nj]
#pragma unroll
    for (int kk = 0; kk < 2; ++kk) {
#pragma unroll
        for (int mh = 0; mh < 2; ++mh)
#pragma unroll
            for (int mi = 0; mi < 4; ++mi) {
                int R = wr * 128 + mh * 64 + mi * 16 + fr;
                offA[kk][mh][mi] = R * 64 + (((kk * 4 + fq) ^ (R & 7)) * 8);
            }
#pragma unroll
        for (int nj = 0; nj < 4; ++nj) {
            int R = wc * 64 + nj * 16 + fr;
            offB[kk][nj] = R * 64 + (((kk * 4 + fq) ^ (R & 7)) * 8);
        }
    }

    f32x4 acc[8][4] = {};

    {   // prologue: tile0 full (8 issues) + tile1 rows{0,128} (4 issues)
        int ao, bo;
        offs(0, ao, bo);
        stage64(&As[0][0], Ab, 0, LDA, ao, w, lane);
        stage64(&As[0][0], Ab, 128, LDA, ao, w, lane);
        stage64(&As[0][0], Ab, 64, LDA, ao, w, lane);
        stage64(&As[0][0], Ab, 192, LDA, ao, w, lane);
        stage64(&Ws[0][0], Bb, 0, LDB, bo, w, lane);
        stage64(&Ws[0][0], Bb, 128, LDB, bo, w, lane);
        stage64(&Ws[0][0], Bb, 64, LDB, bo, w, lane);
        stage64(&Ws[0][0], Bb, 192, LDB, bo, w, lane);
        if (NT > 1) {
            offs(1, ao, bo);
            stage64(&As[1][0], Ab, 0, LDA, ao, w, lane);
            stage64(&As[1][0], Ab, 128, LDA, ao, w, lane);
            stage64(&Ws[1][0], Bb, 0, LDB, bo, w, lane);
            stage64(&Ws[1][0], Bb, 128, LDB, bo, w, lane);
            asm volatile("s_waitcnt vmcnt(4)" ::: "memory");
        } else {
            asm volatile("s_waitcnt vmcnt(0)" ::: "memory");
        }
        __builtin_amdgcn_s_barrier();
    }

    for (int t = 0; t < NT; ++t) {
        const __bf16* Asb = &As[t & 1][0];
        const __bf16* Wsb = &Ws[t & 1][0];
        __bf16* Asn = &As[(t & 1) ^ 1][0];
        __bf16* Wsn = &Ws[(t & 1) ^ 1][0];
        bf16x8 af[4], bfr[4];

        // ---- P1: kk=0, mh=0 ; stage rows{64,192} of t+1 into other buffer ----
        af[0] = *(const bf16x8*)&Asb[offA[0][0][0]];
#pragma unroll
        for (int n = 0; n < 4; ++n) bfr[n] = *(const bf16x8*)&Wsb[offB[0][n]];
#pragma unroll
        for (int i = 1; i < 4; ++i) af[i] = *(const bf16x8*)&Asb[offA[0][0][i]];
        if (t + 1 < NT) {
            int ao, bo;
            offs(t + 1, ao, bo);
            stage64(Asn, Ab, 64, LDA, ao, w, lane);
            stage64(Asn, Ab, 192, LDA, ao, w, lane);
            stage64(Wsn, Bb, 64, LDB, bo, w, lane);
            stage64(Wsn, Bb, 192, LDB, bo, w, lane);
        }
        __builtin_amdgcn_s_barrier();
        __builtin_amdgcn_s_setprio(1);
#pragma unroll
        for (int mi = 0; mi < 4; ++mi)
#pragma unroll
            for (int nj = 0; nj < 4; ++nj)
                acc[mi][nj] = __builtin_amdgcn_mfma_f32_16x16x32_bf16(af[mi], bfr[nj], acc[mi][nj], 0, 0, 0);
        __builtin_amdgcn_s_setprio(0);
        __builtin_amdgcn_s_barrier();

        // ---- P2: kk=0, mh=1 (B frags reused from P1) ----
#pragma unroll
        for (int i = 0; i < 4; ++i) af[i] = *(const bf16x8*)&Asb[offA[0][1][i]];
        __builtin_amdgcn_s_barrier();
        __builtin_amdgcn_s_setprio(1);
#pragma unroll
        for (int mi = 0; mi < 4; ++mi)
#pragma unroll
            for (int nj = 0; nj < 4; ++nj)
                acc[4 + mi][nj] = __builtin_amdgcn_mfma_f32_16x16x32_bf16(af[mi], bfr[nj], acc[4 + mi][nj], 0, 0, 0);
        __builtin_amdgcn_s_setprio(0);
        __builtin_amdgcn_s_barrier();

        // ---- P3: kk=1, mh=0 ----
        af[0] = *(const bf16x8*)&Asb[offA[1][0][0]];
#pragma unroll
        for (int n = 0; n < 4; ++n) bfr[n] = *(const bf16x8*)&Wsb[offB[1][n]];
#pragma unroll
        for (int i = 1; i < 4; ++i) af[i] = *(const bf16x8*)&Asb[offA[1][0][i]];
        __builtin_amdgcn_s_barrier();
        __builtin_amdgcn_s_setprio(1);
#pragma unroll
        for (int mi = 0; mi < 4; ++mi)
#pragma unroll
            for (int nj = 0; nj < 4; ++nj)
                acc[mi][nj] = __builtin_amdgcn_mfma_f32_16x16x32_bf16(af[mi], bfr[nj], acc[mi][nj], 0, 0, 0);
        __builtin_amdgcn_s_setprio(0);
        __builtin_amdgcn_s_barrier();

        // ---- P4: kk=1, mh=1 ; stage rows{0,128} of t+2 into THIS buffer ; vmcnt ----
#pragma unroll
        for (int i = 0; i < 4; ++i) af[i] = *(const bf16x8*)&Asb[offA[1][1][i]];
        if (t + 2 < NT) {
            int ao, bo;
            offs(t + 2, ao, bo);
            stage64((__bf16*)Asb, Ab, 0, LDA, ao, w, lane);
            stage64((__bf16*)Asb, Ab, 128, LDA, ao, w, lane);
            stage64((__bf16*)Wsb, Bb, 0, LDB, bo, w, lane);
            stage64((__bf16*)Wsb, Bb, 128, LDB, bo, w, lane);
            asm volatile("s_waitcnt vmcnt(4)" ::: "memory");   // next tile fully landed; own 4 in flight
        } else {
            asm volatile("s_waitcnt vmcnt(0)" ::: "memory");
        }
        __builtin_amdgcn_s_barrier();
        __builtin_amdgcn_s_setprio(1);
#pragma unroll
        for (int mi = 0; mi < 4; ++mi)
#pragma unroll
            for (int nj = 0; nj < 4; ++nj)
                acc[4 + mi][nj] = __builtin_amdgcn_mfma_f32_16x16x32_bf16(af[mi], bfr[nj], acc[4 + mi][nj], 0, 0, 0);
        __builtin_amdgcn_s_setprio(0);
        __builtin_amdgcn_s_barrier();
    }

    // C/D layout: col = fr, row = fq*4 + reg  [m89/m91 verified]
    if constexpr (EPI == 0) {
        // gelu is quasiconvex (min at x~-0.75): max_s gelu(x) = max(gelu(min x), gelu(max x))
        float* scores = (float*)outp;
#pragma unroll
        for (int nj = 0; nj < 4; ++nj) {
            float mx = -INFINITY, mn = INFINITY;
#pragma unroll
            for (int mi = 0; mi < 8; ++mi)
#pragma unroll
                for (int r = 0; r < 4; ++r) {
                    float v = acc[mi][nj][r];
                    mx = fmaxf(mx, v);
                    mn = fminf(mn, v);
                }
            mx = fmaxf(mx, __shfl_xor(mx, 16));
            mx = fmaxf(mx, __shfl_xor(mx, 32));
            mn = fminf(mn, __shfl_xor(mn, 16));
            mn = fminf(mn, __shfl_xor(mn, 32));
            if (fq == 0) {
                float m = fmaxf(gelu_exact(mx), gelu_exact(mn));
                atomicMaxFloat(&scores[(size_t)b * LDOUT + p0 + wc * 64 + nj * 16 + fr], m);
            }
        }
    } else if constexpr (EPI == 1) {
        __bf16* o = (__bf16*)outp;
#pragma unroll
        for (int mi = 0; mi < 8; ++mi)
#pragma unroll
            for (int r = 0; r < 4; ++r) {
                size_t row = (size_t)b * S + s0 + wr * 128 + mi * 16 + fq * 4 + r;
#pragma unroll
                for (int nj = 0; nj < 4; ++nj)
                    o[row * LDOUT + p0 + wc * 64 + nj * 16 + fr] = (__bf16)gelu_exact(acc[mi][nj][r]);
            }
    } else {
        float* o = (float*)outp;
#pragma unroll
        for (int mi = 0; mi < 8; ++mi)
#pragma unroll
            for (int r = 0; r < 4; ++r) {
                size_t row = (size_t)b * S + s0 + wr * 128 + mi * 16 + fq * 4 + r;
#pragma unroll
                for (int nj = 0; nj < 4; ++nj)
                    o[row * LDOUT + p0 + wc * 64 + nj * 16 + fr] = acc[mi][nj][r];
            }
    }
}

// ---- MLP: read w1/w2 exactly once, loop batches in-register, partial-sum atomics ----
__global__ __launch_bounds__(256) void mlp1_part(const float* __restrict__ w1,
                                                 const unsigned* __restrict__ maskb,
                                                 float* __restrict__ hacc) {
    __shared__ unsigned smb[512];
    int i0 = blockIdx.x * 64;
    int c0 = blockIdx.y * 512;
    int tid = threadIdx.x;
    for (int c = tid; c < 512; c += 256) smb[c] = maskb[c0 + c];
    __syncthreads();
    int r = tid >> 2, cq = tid & 3;
    const float* row = w1 + (size_t)(i0 + r) * NIN + c0;
    float acc[B] = {};
    for (int it = 0; it < 32; ++it) {
        int c = it * 16 + cq * 4;
        float4 v = *(const float4*)(row + c);
        float vv[4] = {v.x, v.y, v.z, v.w};
#pragma unroll
        for (int e = 0; e < 4; ++e) {
            unsigned mb = smb[c + e];
#pragma unroll
            for (int bb = 0; bb < B; ++bb)
                if (mb & (1u << bb)) acc[bb] += vv[e];
        }
    }
#pragma unroll
    for (int bb = 0; bb < B; ++bb)
        atomicAdd(&hacc[bb * HID + i0 + r], acc[bb]);
}

__global__ __launch_bounds__(256) void fin1(const float* __restrict__ hacc,
                                            const float* __restrict__ b1,
                                            float* __restrict__ h) {
    int t = blockIdx.x * 256 + threadIdx.x;
    if (t < B * HID) h[t] = gelu_exact(hacc[t] + b1[t & (HID - 1)]);
}

__global__ __launch_bounds__(256) void mlp2_part(const float* __restrict__ w2,
                                                 const float* __restrict__ h,
                                                 float* __restrict__ relacc) {
    __shared__ float sh[B][512];
    int p0 = blockIdx.x * 64;
    int c0 = blockIdx.y * 512;
    int tid = threadIdx.x;
    for (int i = tid; i < B * 128; i += 256) {
        int bb = i >> 7, c4 = i & 127;
        *(float4*)&sh[bb][c4 * 4] = *(const float4*)&h[(size_t)bb * HID + c0 + c4 * 4];
    }
    __syncthreads();
    int r = tid >> 2, cq = tid & 3;
    const float* row = w2 + (size_t)(p0 + r) * HID + c0;
    float acc[B] = {};
    for (int it = 0; it < 32; ++it) {
        int c = it * 16 + cq * 4;
        float4 v = *(const float4*)(row + c);
#pragma unroll
        for (int bb = 0; bb < B; ++bb)
            acc[bb] += v.x * sh[bb][c] + v.y * sh[bb][c + 1] + v.z * sh[bb][c + 2] + v.w * sh[bb][c + 3];
    }
#pragma unroll
    for (int bb = 0; bb < B; ++bb)
        atomicAdd(&relacc[bb * NP + p0 + r], acc[bb]);
}

// Exact top-k set via rank counting, jax.lax.top_k tie-break (lower index wins).
// fin2 (sigmoid gating) fused into the LDS fill: identical float math in every
// block -> consistent sc[] across blocks.
__global__ __launch_bounds__(256) void topk_select(const float* __restrict__ scores,
                                                   const float* __restrict__ relacc,
                                                   const float* __restrict__ b2,
                                                   int* __restrict__ selidx,
                                                   int* __restrict__ selcnt) {
    __shared__ float sc[NP];
    int b = blockIdx.y;
    int p = blockIdx.x * 256 + threadIdx.x;
    for (int c = threadIdx.x; c < NP; c += 256) {
        float rel = relacc[(size_t)b * NP + c] + b2[c];
        sc[c] = scores[(size_t)b * NP + c] * (1.0f / (1.0f + expf(-rel)));
    }
    __syncthreads();
    float my = sc[p];
    int cnt = 0;
    for (int q = 0; q < NP; ++q) {
        float v = sc[q];
        cnt += (v > my) || (v == my && q < p);
    }
    if (cnt < TOPK) {
        int pos = atomicAdd(&selcnt[b], 1);
        selidx[b * TOPK + pos] = p;  // order arbitrary; final einsum is a sum
    }
}

// Wsel[b][kk][0:512] = Wpack[b][sel[kk]][0:512]  (hi half only)
__global__ __launch_bounds__(256) void wsel_gather(const __bf16* __restrict__ wpack,
                                                   const int* __restrict__ selidx,
                                                   __bf16* __restrict__ wsel) {
    int kk = blockIdx.x, b = blockIdx.y;
    int sel = selidx[b * TOPK + kk];
    const unsigned* src = (const unsigned*)(wpack + ((size_t)b * NP + sel) * 1024);
    unsigned* dst = (unsigned*)(wsel + ((size_t)b * TOPK + kk) * 512);
    dst[threadIdx.x] = src[threadIdx.x];  // 256 uints = 512 bf16
}

// PT[b][d][kk] = bf16(proj[sel[kk]][d])  via LDS transpose
__global__ __launch_bounds__(256) void projT_gather(const float* __restrict__ proj,
                                                    const int* __restrict__ selidx,
                                                    __bf16* __restrict__ PT) {
    __shared__ float tile[64][68];
    __shared__ int sel[64];
    int b = blockIdx.z, d0 = blockIdx.x * 64, k0 = blockIdx.y * 64;
    int tid = threadIdx.x;
    if (tid < 64) sel[tid] = selidx[b * TOPK + k0 + tid];
    __syncthreads();
    for (int r = 0; r < 4; ++r) {
        int kk = r * 16 + (tid >> 4);
        float4 v = *(const float4*)&proj[(size_t)sel[kk] * DM + d0 + (tid & 15) * 4];
        *(float4*)&tile[kk][(tid & 15) * 4] = v;
    }
    __syncthreads();
    for (int r = 0; r < 16; ++r) {
        int dd = r * 4 + (tid >> 6);
        int kk = tid & 63;
        PT[((size_t)b * DM + d0 + dd) * TOPK + k0 + kk] = (__bf16)tile[kk][dd];
    }
}

extern "C" void kernel_launch(void* const* d_in, const int* in_sizes, int n_in,
                              void* d_out, int out_size, void* d_ws, size_t ws_size,
                              hipStream_t stream) {
    const float* A    = (const float*)d_in[0];
    const int*   idx  = (const int*)d_in[1];
    const float* cw   = (const float*)d_in[3];
    const float* proj = (const float*)d_in[4];
    const float* w1   = (const float*)d_in[5];
    const float* b1   = (const float*)d_in[6];
    const float* w2   = (const float*)d_in[7];
    const float* b2   = (const float*)d_in[8];
    float* out = (float*)d_out;

    char* ws = (char*)d_ws;
    size_t off = 0;
    auto alloc = [&](size_t bytes) {
        void* p = ws + off;
        off += (bytes + 255) & ~(size_t)255;
        return p;
    };
    __bf16* Apack = (__bf16*)alloc((size_t)B * S * 1024 * 2);    // 33.5 MB
    __bf16* Wpack = (__bf16*)alloc((size_t)B * NP * 1024 * 2);   // 67 MB
    __bf16* selpa = (__bf16*)alloc((size_t)B * S * TOPK * 2);    // 8.4 MB
    __bf16* PT    = (__bf16*)alloc((size_t)B * DM * TOPK * 2);   // 4.2 MB
    __bf16* Wsel  = (__bf16*)alloc((size_t)B * TOPK * 512 * 2);  // 2.1 MB
    float* scores = (float*)alloc((size_t)B * NP * 4);
    float* relacc = (float*)alloc((size_t)B * NP * 4);
    float* hacc   = (float*)alloc((size_t)B * HID * 4);
    float* h      = (float*)alloc((size_t)B * HID * 4);
    unsigned* maskb = (unsigned*)alloc((size_t)NIN * 4);
    int* selidx   = (int*)alloc((size_t)B * TOPK * 4);
    int* selcnt   = (int*)alloc((size_t)B * 4);

    init_kernel<<<dim3((B * HID + 255) / 256), 256, 0, stream>>>(scores, relacc, hacc, maskb, selcnt);
    scatter_maskbits<<<dim3((B * KIN + 255) / 256), 256, 0, stream>>>(idx, maskb);
    pack_A<<<dim3((B * S * KIN / 4) / 256), 256, 0, stream>>>(A, Apack);
    gather_pack_w<<<dim3(NP / 4), 256, 0, stream>>>(cw, idx, Wpack);

    // scores: split-fp32 (3 segments) bf16 MFMA, 256^2 pipeline (compiler-managed
    // lgkm waits) + XCD remap, fused max+gelu epilogue
    mfma_gemm256<0, 3, 512, 1024, 1024, NP, NP>
        <<<dim3(S / 256, NP / 256, B), 512, 0, stream>>>(Apack, Wpack, (void*)scores);

    mlp1_part<<<dim3(HID / 64, NIN / 512), 256, 0, stream>>>(w1, maskb, hacc);
    fin1<<<dim3((B * HID + 255) / 256), 256, 0, stream>>>(hacc, b1, h);
    mlp2_part<<<dim3(NP / 64, HID / 512), 256, 0, stream>>>(w2, h, relacc);

    topk_select<<<dim3(NP / 256, B), 256, 0, stream>>>(scores, relacc, b2, selidx, selcnt);

    wsel_gather<<<dim3(TOPK, B), 256, 0, stream>>>(Wpack, selidx, Wsel);
    projT_gather<<<dim3(DM / 64, TOPK / 64, B), 256, 0, stream>>>(proj, selidx, PT);

    // selpa = gelu(A * Wsel^T) in bf16 (hi-only, 1 segment)
    mfma_gemm<1, 1, 512, 1024, 512, TOPK, TOPK>
        <<<dim3(S / 128, TOPK / 128, B), 256, 0, stream>>>(Apack, Wsel, (void*)selpa);

    // out = selpa * PT^T  (K=256, fp32 store)
    mfma_gemm<2, 1, 256, 256, 256, DM, DM>
        <<<dim3(S / 128, DM / 128, B), 256, 0, stream>>>(selpa, PT, (void*)out);
}

// Round 5
// 634.123 us; speedup vs baseline: 1.1017x; 1.0337x over previous
//
#include <hip/hip_runtime.h>
#include <math.h>

#define B 8
#define S 2048
#define KIN 512
#define NIN 2048
#define NP 4096
#define HID 4096
#define DM 1024
#define TOPK 256

typedef __bf16 bf16x8 __attribute__((ext_vector_type(8)));
typedef __bf16 bf16x4 __attribute__((ext_vector_type(4)));
typedef float f32x4 __attribute__((ext_vector_type(4)));

__device__ __forceinline__ float gelu_exact(float x) {
    return 0.5f * x * (1.0f + erff(x * 0.70710678118654752440f));
}

__device__ __forceinline__ void atomicMaxFloat(float* addr, float val) {
    if (val >= 0.0f) atomicMax((int*)addr, __float_as_int(val));
    else             atomicMin((unsigned int*)addr, __float_as_uint(val));
}

// async 16B/lane global->LDS; lds base must be wave-uniform, lane l lands at base + l*16
__device__ __forceinline__ void async_copy16(void* lds, const void* g) {
    __builtin_amdgcn_global_load_lds(
        (__attribute__((address_space(1))) void*)g,
        (__attribute__((address_space(3))) void*)lds, 16, 0, 0);
}

__global__ __launch_bounds__(256) void init_kernel(float* scores, float* relacc,
                                                   float* hacc, unsigned* maskb,
                                                   int* selcnt) {
    int t = blockIdx.x * blockDim.x + threadIdx.x;
    if (t < B * NP)  { scores[t] = __int_as_float(0xFF800000); relacc[t] = 0.f; }
    if (t < B * HID) hacc[t] = 0.f;
    if (t < NIN)     maskb[t] = 0u;
    if (t < B)       selcnt[t] = 0;
}

__global__ __launch_bounds__(256) void scatter_maskbits(const int* __restrict__ idx,
                                                        unsigned* __restrict__ maskb) {
    int t = blockIdx.x * blockDim.x + threadIdx.x;
    if (t >= B * KIN) return;
    int b = t / KIN;
    atomicOr(&maskb[idx[t]], 1u << b);
}

// A fp32 [B][S][512] -> Apack bf16 [B][S][1024] = {hi(512) | lo(512)}
__global__ __launch_bounds__(256) void pack_A(const float* __restrict__ A,
                                              __bf16* __restrict__ Apack) {
    size_t t = (size_t)blockIdx.x * 256 + threadIdx.x;  // float4 index
    size_t f = t * 4;
    size_t rowi = f >> 9;
    int j = (int)(f & 511);
    float4 v = *(const float4*)(A + f);
    __bf16 h0 = (__bf16)v.x, h1 = (__bf16)v.y, h2 = (__bf16)v.z, h3 = (__bf16)v.w;
    bf16x4 hv = {h0, h1, h2, h3};
    bf16x4 lv = {(__bf16)(v.x - (float)h0), (__bf16)(v.y - (float)h1),
                 (__bf16)(v.z - (float)h2), (__bf16)(v.w - (float)h3)};
    __bf16* orow = Apack + rowi * 1024;
    *(bf16x4*)(orow + j) = hv;
    *(bf16x4*)(orow + 512 + j) = lv;
}

// One pass over cw: each block owns 4 cw rows in LDS, gathers for all 8 batches.
// Writes vectorized: each thread builds 8 consecutive j as bf16x8 (hi & lo).
__global__ __launch_bounds__(256) void gather_pack_w(const float* __restrict__ cw,
                                                     const int* __restrict__ idx,
                                                     __bf16* __restrict__ wpack) {
    __shared__ float rowbuf[4][NIN];   // 32 KB
    __shared__ int sidx[B][KIN];       // 16 KB
    int p0 = blockIdx.x * 4;
    int tid = threadIdx.x;
    for (int t = tid; t < B * KIN; t += 256) sidx[t >> 9][t & 511] = idx[t];
#pragma unroll
    for (int r = 0; r < 4; ++r)
        for (int c = tid; c < NIN / 4; c += 256)
            *(float4*)&rowbuf[r][c * 4] = *(const float4*)&cw[(size_t)(p0 + r) * NIN + c * 4];
    __syncthreads();
#pragma unroll
    for (int it = 0; it < 8; ++it) {
        int combo = it * 4 + (tid >> 6);   // 0..31 = r*8 + b
        int r = combo >> 3, bb = combo & 7;
        int j0 = (tid & 63) * 8;
        bf16x8 hv, lv;
#pragma unroll
        for (int e = 0; e < 8; ++e) {
            float x = rowbuf[r][sidx[bb][j0 + e]];
            __bf16 hh = (__bf16)x;
            hv[e] = hh;
            lv[e] = (__bf16)(x - (float)hh);
        }
        __bf16* orow = wpack + ((size_t)bb * NP + p0 + r) * 1024;
        *(bf16x8*)(orow + j0) = hv;
        *(bf16x8*)(orow + 512 + j0) = lv;
    }
}

// ---------------- 128x128 MFMA GEMM (kept for the two small GEMMs) ----------------
// EPI: 1 = gelu -> bf16 out ; 2 = raw fp32 out
template <int EPI, int NSEG, int KSEG, int LDA, int LDB, int BROWS, int LDOUT>
__global__ __launch_bounds__(256) void mfma_gemm(const __bf16* __restrict__ Ap,
                                                 const __bf16* __restrict__ Bp,
                                                 void* __restrict__ outp) {
    __shared__ __align__(16) __bf16 As[128 * 64];
    __shared__ __align__(16) __bf16 Ws[128 * 64];
    const int b = blockIdx.z;
    const int s0 = blockIdx.x * 128;
    const int p0 = blockIdx.y * 128;
    const int tid = threadIdx.x;
    const int w = tid >> 6, lane = tid & 63;
    const int wr = w >> 1, wc = w & 1;
    const int ldRow = lane >> 3;
    const int ldCol = ((lane & 7) ^ (ldRow & 7)) * 8;
    const int fr = lane & 15;
    const int fq = lane >> 4;
    const __bf16* Ab = Ap + ((size_t)b * S + s0) * LDA;
    const __bf16* Bb = Bp + ((size_t)b * BROWS + p0) * LDB;

    f32x4 acc[4][4] = {};

    for (int seg = 0; seg < NSEG; ++seg) {
        const int aoff = (seg == 1) ? KSEG : 0;
        const int boff = (seg == 2) ? KSEG : 0;
        for (int k0 = 0; k0 < KSEG; k0 += 64) {
            __syncthreads();
#pragma unroll
            for (int i = 0; i < 4; ++i) {
                const __bf16* g = Ab + (size_t)(w * 32 + i * 8 + ldRow) * LDA + aoff + k0 + ldCol;
                async_copy16(&As[(w * 32 + i * 8) * 64], g);
            }
#pragma unroll
            for (int i = 0; i < 4; ++i) {
                const __bf16* g = Bb + (size_t)(w * 32 + i * 8 + ldRow) * LDB + boff + k0 + ldCol;
                async_copy16(&Ws[(w * 32 + i * 8) * 64], g);
            }
            __syncthreads();
#pragma unroll
            for (int ks = 0; ks < 2; ++ks) {
                bf16x8 af[4], bfr[4];
#pragma unroll
                for (int i = 0; i < 4; ++i) {
                    int R = wr * 64 + i * 16 + fr;
                    af[i] = *(const bf16x8*)&As[R * 64 + (((ks * 4 + fq) ^ (R & 7)) * 8)];
                }
#pragma unroll
                for (int j = 0; j < 4; ++j) {
                    int R = wc * 64 + j * 16 + fr;
                    bfr[j] = *(const bf16x8*)&Ws[R * 64 + (((ks * 4 + fq) ^ (R & 7)) * 8)];
                }
#pragma unroll
                for (int i = 0; i < 4; ++i)
#pragma unroll
                    for (int j = 0; j < 4; ++j)
                        acc[i][j] = __builtin_amdgcn_mfma_f32_16x16x32_bf16(af[i], bfr[j], acc[i][j], 0, 0, 0);
            }
        }
    }

    if constexpr (EPI == 1) {
        __bf16* o = (__bf16*)outp;
#pragma unroll
        for (int i = 0; i < 4; ++i)
#pragma unroll
            for (int r = 0; r < 4; ++r) {
                size_t row = (size_t)b * S + s0 + wr * 64 + i * 16 + fq * 4 + r;
#pragma unroll
                for (int j = 0; j < 4; ++j)
                    o[row * LDOUT + p0 + wc * 64 + j * 16 + fr] = (__bf16)gelu_exact(acc[i][j][r]);
            }
    } else {
        float* o = (float*)outp;
#pragma unroll
        for (int i = 0; i < 4; ++i)
#pragma unroll
            for (int r = 0; r < 4; ++r) {
                size_t row = (size_t)b * S + s0 + wr * 64 + i * 16 + fq * 4 + r;
#pragma unroll
                for (int j = 0; j < 4; ++j)
                    o[row * LDOUT + p0 + wc * 64 + j * 16 + fr] = acc[i][j][r];
            }
    }
}

// ---------------- 256x256 8-wave pipelined MFMA GEMM (scores GEMM) ----------------
// R4 structure (two barriers/phase, stage at P1/P4, vmcnt(4) never 0, setprio,
// XCD remap, compiler-managed fine-grained lgkm waits). UNCHANGED vs R4.
__device__ __forceinline__ void stage64(__bf16* ldsTile, const __bf16* gRow0,
                                        int rbase, int ldg, int koff, int w, int lane) {
    const int rr = lane >> 3;                 // 0..7 rows per wave per issue
    const int gc = ((lane & 7) ^ rr) * 8;     // pre-swizzled global chunk
    const __bf16* g = gRow0 + (size_t)(rbase + w * 8 + rr) * ldg + (koff + gc);
    async_copy16(ldsTile + (rbase + w * 8) * 64, g);  // wave-uniform LDS base
}

template <int EPI, int NSEG, int KSEG, int LDA, int LDB, int BROWS, int LDOUT>
__global__ __launch_bounds__(512, 2) void mfma_gemm256(const __bf16* __restrict__ Ap,
                                                       const __bf16* __restrict__ Bp,
                                                       void* __restrict__ outp) {
    constexpr int TPS = KSEG / 64;
    constexpr int NT = NSEG * TPS;
    __shared__ __align__(16) __bf16 As[2][256 * 64];  // 2 x 32 KB
    __shared__ __align__(16) __bf16 Ws[2][256 * 64];  // 2 x 32 KB

    // XCD-aware remap (grid fixed at (8,16,8); dispatch order x-fastest, XCD = flat%8)
    const int flat = blockIdx.x + (blockIdx.y << 3) + (blockIdx.z << 7);
    const int b = flat & 7;                 // batch == XCD
    const int j = flat >> 3;                // 0..127 within XCD
    const int s0 = (j & 7) * 256;           // S tile (inner: concurrent blocks share A)
    const int p0 = (j >> 3) * 256;          // NP tile

    const int tid = threadIdx.x;
    const int w = tid >> 6, lane = tid & 63;
    const int wr = w >> 2, wc = w & 3;        // 2 x 4 wave grid, each owns 128x64
    const int fr = lane & 15, fq = lane >> 4;
    const __bf16* Ab = Ap + ((size_t)b * S + s0) * LDA;
    const __bf16* Bb = Bp + ((size_t)b * BROWS + p0) * LDB;

    auto offs = [&](int t, int& ao, int& bo) {
        int seg = t / TPS, k0 = (t % TPS) * 64;
        ao = ((NSEG == 3 && seg == 1) ? KSEG : 0) + k0;
        bo = ((NSEG == 3 && seg == 2) ? KSEG : 0) + k0;
    };

    // Hoisted LDS-read offsets (loop-invariant; static indexing only -> registers)
    int offA[2][2][4];  // [kk][mh][mi]
    int offB[2][4];     // [kk][nj]
#pragma unroll
    for (int kk = 0; kk < 2; ++kk) {
#pragma unroll
        for (int mh = 0; mh < 2; ++mh)
#pragma unroll
            for (int mi = 0; mi < 4; ++mi) {
                int R = wr * 128 + mh * 64 + mi * 16 + fr;
                offA[kk][mh][mi] = R * 64 + (((kk * 4 + fq) ^ (R & 7)) * 8);
            }
#pragma unroll
        for (int nj = 0; nj < 4; ++nj) {
            int R = wc * 64 + nj * 16 + fr;
            offB[kk][nj] = R * 64 + (((kk * 4 + fq) ^ (R & 7)) * 8);
        }
    }

    f32x4 acc[8][4] = {};

    {   // prologue: tile0 full (8 issues) + tile1 rows{0,128} (4 issues)
        int ao, bo;
        offs(0, ao, bo);
        stage64(&As[0][0], Ab, 0, LDA, ao, w, lane);
        stage64(&As[0][0], Ab, 128, LDA, ao, w, lane);
        stage64(&As[0][0], Ab, 64, LDA, ao, w, lane);
        stage64(&As[0][0], Ab, 192, LDA, ao, w, lane);
        stage64(&Ws[0][0], Bb, 0, LDB, bo, w, lane);
        stage64(&Ws[0][0], Bb, 128, LDB, bo, w, lane);
        stage64(&Ws[0][0], Bb, 64, LDB, bo, w, lane);
        stage64(&Ws[0][0], Bb, 192, LDB, bo, w, lane);
        if (NT > 1) {
            offs(1, ao, bo);
            stage64(&As[1][0], Ab, 0, LDA, ao, w, lane);
            stage64(&As[1][0], Ab, 128, LDA, ao, w, lane);
            stage64(&Ws[1][0], Bb, 0, LDB, bo, w, lane);
            stage64(&Ws[1][0], Bb, 128, LDB, bo, w, lane);
            asm volatile("s_waitcnt vmcnt(4)" ::: "memory");
        } else {
            asm volatile("s_waitcnt vmcnt(0)" ::: "memory");
        }
        __builtin_amdgcn_s_barrier();
    }

    for (int t = 0; t < NT; ++t) {
        const __bf16* Asb = &As[t & 1][0];
        const __bf16* Wsb = &Ws[t & 1][0];
        __bf16* Asn = &As[(t & 1) ^ 1][0];
        __bf16* Wsn = &Ws[(t & 1) ^ 1][0];
        bf16x8 af[4], bfr[4];

        // ---- P1: kk=0, mh=0 ; stage rows{64,192} of t+1 into other buffer ----
        af[0] = *(const bf16x8*)&Asb[offA[0][0][0]];
#pragma unroll
        for (int n = 0; n < 4; ++n) bfr[n] = *(const bf16x8*)&Wsb[offB[0][n]];
#pragma unroll
        for (int i = 1; i < 4; ++i) af[i] = *(const bf16x8*)&Asb[offA[0][0][i]];
        if (t + 1 < NT) {
            int ao, bo;
            offs(t + 1, ao, bo);
            stage64(Asn, Ab, 64, LDA, ao, w, lane);
            stage64(Asn, Ab, 192, LDA, ao, w, lane);
            stage64(Wsn, Bb, 64, LDB, bo, w, lane);
            stage64(Wsn, Bb, 192, LDB, bo, w, lane);
        }
        __builtin_amdgcn_s_barrier();
        __builtin_amdgcn_s_setprio(1);
#pragma unroll
        for (int mi = 0; mi < 4; ++mi)
#pragma unroll
            for (int nj = 0; nj < 4; ++nj)
                acc[mi][nj] = __builtin_amdgcn_mfma_f32_16x16x32_bf16(af[mi], bfr[nj], acc[mi][nj], 0, 0, 0);
        __builtin_amdgcn_s_setprio(0);
        __builtin_amdgcn_s_barrier();

        // ---- P2: kk=0, mh=1 (B frags reused from P1) ----
#pragma unroll
        for (int i = 0; i < 4; ++i) af[i] = *(const bf16x8*)&Asb[offA[0][1][i]];
        __builtin_amdgcn_s_barrier();
        __builtin_amdgcn_s_setprio(1);
#pragma unroll
        for (int mi = 0; mi < 4; ++mi)
#pragma unroll
            for (int nj = 0; nj < 4; ++nj)
                acc[4 + mi][nj] = __builtin_amdgcn_mfma_f32_16x16x32_bf16(af[mi], bfr[nj], acc[4 + mi][nj], 0, 0, 0);
        __builtin_amdgcn_s_setprio(0);
        __builtin_amdgcn_s_barrier();

        // ---- P3: kk=1, mh=0 ----
        af[0] = *(const bf16x8*)&Asb[offA[1][0][0]];
#pragma unroll
        for (int n = 0; n < 4; ++n) bfr[n] = *(const bf16x8*)&Wsb[offB[1][n]];
#pragma unroll
        for (int i = 1; i < 4; ++i) af[i] = *(const bf16x8*)&Asb[offA[1][0][i]];
        __builtin_amdgcn_s_barrier();
        __builtin_amdgcn_s_setprio(1);
#pragma unroll
        for (int mi = 0; mi < 4; ++mi)
#pragma unroll
            for (int nj = 0; nj < 4; ++nj)
                acc[mi][nj] = __builtin_amdgcn_mfma_f32_16x16x32_bf16(af[mi], bfr[nj], acc[mi][nj], 0, 0, 0);
        __builtin_amdgcn_s_setprio(0);
        __builtin_amdgcn_s_barrier();

        // ---- P4: kk=1, mh=1 ; stage rows{0,128} of t+2 into THIS buffer ; vmcnt ----
#pragma unroll
        for (int i = 0; i < 4; ++i) af[i] = *(const bf16x8*)&Asb[offA[1][1][i]];
        if (t + 2 < NT) {
            int ao, bo;
            offs(t + 2, ao, bo);
            stage64((__bf16*)Asb, Ab, 0, LDA, ao, w, lane);
            stage64((__bf16*)Asb, Ab, 128, LDA, ao, w, lane);
            stage64((__bf16*)Wsb, Bb, 0, LDB, bo, w, lane);
            stage64((__bf16*)Wsb, Bb, 128, LDB, bo, w, lane);
            asm volatile("s_waitcnt vmcnt(4)" ::: "memory");   // next tile fully landed; own 4 in flight
        } else {
            asm volatile("s_waitcnt vmcnt(0)" ::: "memory");
        }
        __builtin_amdgcn_s_barrier();
        __builtin_amdgcn_s_setprio(1);
#pragma unroll
        for (int mi = 0; mi < 4; ++mi)
#pragma unroll
            for (int nj = 0; nj < 4; ++nj)
                acc[4 + mi][nj] = __builtin_amdgcn_mfma_f32_16x16x32_bf16(af[mi], bfr[nj], acc[4 + mi][nj], 0, 0, 0);
        __builtin_amdgcn_s_setprio(0);
        __builtin_amdgcn_s_barrier();
    }

    // C/D layout: col = fr, row = fq*4 + reg  [m89/m91 verified]
    if constexpr (EPI == 0) {
        // gelu is quasiconvex (min at x~-0.75): max_s gelu(x) = max(gelu(min x), gelu(max x))
        float* scores = (float*)outp;
#pragma unroll
        for (int nj = 0; nj < 4; ++nj) {
            float mx = -INFINITY, mn = INFINITY;
#pragma unroll
            for (int mi = 0; mi < 8; ++mi)
#pragma unroll
                for (int r = 0; r < 4; ++r) {
                    float v = acc[mi][nj][r];
                    mx = fmaxf(mx, v);
                    mn = fminf(mn, v);
                }
            mx = fmaxf(mx, __shfl_xor(mx, 16));
            mx = fmaxf(mx, __shfl_xor(mx, 32));
            mn = fminf(mn, __shfl_xor(mn, 16));
            mn = fminf(mn, __shfl_xor(mn, 32));
            if (fq == 0) {
                float m = fmaxf(gelu_exact(mx), gelu_exact(mn));
                atomicMaxFloat(&scores[(size_t)b * LDOUT + p0 + wc * 64 + nj * 16 + fr], m);
            }
        }
    } else if constexpr (EPI == 1) {
        __bf16* o = (__bf16*)outp;
#pragma unroll
        for (int mi = 0; mi < 8; ++mi)
#pragma unroll
            for (int r = 0; r < 4; ++r) {
                size_t row = (size_t)b * S + s0 + wr * 128 + mi * 16 + fq * 4 + r;
#pragma unroll
                for (int nj = 0; nj < 4; ++nj)
                    o[row * LDOUT + p0 + wc * 64 + nj * 16 + fr] = (__bf16)gelu_exact(acc[mi][nj][r]);
            }
    } else {
        float* o = (float*)outp;
#pragma unroll
        for (int mi = 0; mi < 8; ++mi)
#pragma unroll
            for (int r = 0; r < 4; ++r) {
                size_t row = (size_t)b * S + s0 + wr * 128 + mi * 16 + fq * 4 + r;
#pragma unroll
                for (int nj = 0; nj < 4; ++nj)
                    o[row * LDOUT + p0 + wc * 64 + nj * 16 + fr] = acc[mi][nj][r];
            }
    }
}

// ---- MLP: read w1/w2 exactly once, loop batches in-register, partial-sum atomics ----
__global__ __launch_bounds__(256) void mlp1_part(const float* __restrict__ w1,
                                                 const unsigned* __restrict__ maskb,
                                                 float* __restrict__ hacc) {
    __shared__ unsigned smb[512];
    int i0 = blockIdx.x * 64;
    int c0 = blockIdx.y * 512;
    int tid = threadIdx.x;
    for (int c = tid; c < 512; c += 256) smb[c] = maskb[c0 + c];
    __syncthreads();
    int r = tid >> 2, cq = tid & 3;
    const float* row = w1 + (size_t)(i0 + r) * NIN + c0;
    float acc[B] = {};
    for (int it = 0; it < 32; ++it) {
        int c = it * 16 + cq * 4;
        float4 v = *(const float4*)(row + c);
        float vv[4] = {v.x, v.y, v.z, v.w};
#pragma unroll
        for (int e = 0; e < 4; ++e) {
            unsigned mb = smb[c + e];
#pragma unroll
            for (int bb = 0; bb < B; ++bb)
                if (mb & (1u << bb)) acc[bb] += vv[e];
        }
    }
#pragma unroll
    for (int bb = 0; bb < B; ++bb)
        atomicAdd(&hacc[bb * HID + i0 + r], acc[bb]);
}

// mlp2 with fin1 fused: LDS fill applies gelu(hacc + b1) directly.
__global__ __launch_bounds__(256) void mlp2_part(const float* __restrict__ w2,
                                                 const float* __restrict__ hacc,
                                                 const float* __restrict__ b1,
                                                 float* __restrict__ relacc) {
    __shared__ float sh[B][512];
    int p0 = blockIdx.x * 64;
    int c0 = blockIdx.y * 512;
    int tid = threadIdx.x;
    for (int i = tid; i < B * 128; i += 256) {
        int bb = i >> 7, c4 = i & 127;
        float4 a = *(const float4*)&hacc[(size_t)bb * HID + c0 + c4 * 4];
        float4 bias = *(const float4*)&b1[c0 + c4 * 4];
        sh[bb][c4 * 4 + 0] = gelu_exact(a.x + bias.x);
        sh[bb][c4 * 4 + 1] = gelu_exact(a.y + bias.y);
        sh[bb][c4 * 4 + 2] = gelu_exact(a.z + bias.z);
        sh[bb][c4 * 4 + 3] = gelu_exact(a.w + bias.w);
    }
    __syncthreads();
    int r = tid >> 2, cq = tid & 3;
    const float* row = w2 + (size_t)(p0 + r) * HID + c0;
    float acc[B] = {};
    for (int it = 0; it < 32; ++it) {
        int c = it * 16 + cq * 4;
        float4 v = *(const float4*)(row + c);
#pragma unroll
        for (int bb = 0; bb < B; ++bb)
            acc[bb] += v.x * sh[bb][c] + v.y * sh[bb][c + 1] + v.z * sh[bb][c + 2] + v.w * sh[bb][c + 3];
    }
#pragma unroll
    for (int bb = 0; bb < B; ++bb)
        atomicAdd(&relacc[bb * NP + p0 + r], acc[bb]);
}

// Exact top-k set via rank counting, jax.lax.top_k tie-break (lower index wins).
// fin2 (sigmoid gating) fused into the LDS fill. Rank loop vectorized:
// float4 LDS broadcast reads + 4 independent accumulators (the old scalar
// 4096-iter dependent ds_read chain at 0.5 waves/SIMD was latency-serial).
__global__ __launch_bounds__(256) void topk_select(const float* __restrict__ scores,
                                                   const float* __restrict__ relacc,
                                                   const float* __restrict__ b2,
                                                   int* __restrict__ selidx,
                                                   int* __restrict__ selcnt) {
    __shared__ __align__(16) float sc[NP];
    int b = blockIdx.y;
    int p = blockIdx.x * 256 + threadIdx.x;
    for (int c = threadIdx.x; c < NP; c += 256) {
        float rel = relacc[(size_t)b * NP + c] + b2[c];
        sc[c] = scores[(size_t)b * NP + c] * (1.0f / (1.0f + expf(-rel)));
    }
    __syncthreads();
    float my = sc[p];
    int cnt0 = 0, cnt1 = 0, cnt2 = 0, cnt3 = 0;
    const float4* s4 = (const float4*)sc;
#pragma unroll 8
    for (int i = 0; i < NP / 4; ++i) {
        float4 v = s4[i];
        int q = i * 4;
        cnt0 += (int)(v.x > my) | ((int)(v.x == my) & (int)(q < p));
        cnt1 += (int)(v.y > my) | ((int)(v.y == my) & (int)(q + 1 < p));
        cnt2 += (int)(v.z > my) | ((int)(v.z == my) & (int)(q + 2 < p));
        cnt3 += (int)(v.w > my) | ((int)(v.w == my) & (int)(q + 3 < p));
    }
    int cnt = (cnt0 + cnt1) + (cnt2 + cnt3);
    if (cnt < TOPK) {
        int pos = atomicAdd(&selcnt[b], 1);
        selidx[b * TOPK + pos] = p;  // order arbitrary; final einsum is a sum
    }
}

// Wsel[b][kk][0:512] = Wpack[b][sel[kk]][0:512]  (hi half only)
__global__ __launch_bounds__(256) void wsel_gather(const __bf16* __restrict__ wpack,
                                                   const int* __restrict__ selidx,
                                                   __bf16* __restrict__ wsel) {
    int kk = blockIdx.x, b = blockIdx.y;
    int sel = selidx[b * TOPK + kk];
    const unsigned* src = (const unsigned*)(wpack + ((size_t)b * NP + sel) * 1024);
    unsigned* dst = (unsigned*)(wsel + ((size_t)b * TOPK + kk) * 512);
    dst[threadIdx.x] = src[threadIdx.x];  // 256 uints = 512 bf16
}

// PT[b][d][kk] = bf16(proj[sel[kk]][d])  via LDS transpose
__global__ __launch_bounds__(256) void projT_gather(const float* __restrict__ proj,
                                                    const int* __restrict__ selidx,
                                                    __bf16* __restrict__ PT) {
    __shared__ float tile[64][68];
    __shared__ int sel[64];
    int b = blockIdx.z, d0 = blockIdx.x * 64, k0 = blockIdx.y * 64;
    int tid = threadIdx.x;
    if (tid < 64) sel[tid] = selidx[b * TOPK + k0 + tid];
    __syncthreads();
    for (int r = 0; r < 4; ++r) {
        int kk = r * 16 + (tid >> 4);
        float4 v = *(const float4*)&proj[(size_t)sel[kk] * DM + d0 + (tid & 15) * 4];
        *(float4*)&tile[kk][(tid & 15) * 4] = v;
    }
    __syncthreads();
    for (int r = 0; r < 16; ++r) {
        int dd = r * 4 + (tid >> 6);
        int kk = tid & 63;
        PT[((size_t)b * DM + d0 + dd) * TOPK + k0 + kk] = (__bf16)tile[kk][dd];
    }
}

extern "C" void kernel_launch(void* const* d_in, const int* in_sizes, int n_in,
                              void* d_out, int out_size, void* d_ws, size_t ws_size,
                              hipStream_t stream) {
    const float* A    = (const float*)d_in[0];
    const int*   idx  = (const int*)d_in[1];
    const float* cw   = (const float*)d_in[3];
    const float* proj = (const float*)d_in[4];
    const float* w1   = (const float*)d_in[5];
    const float* b1   = (const float*)d_in[6];
    const float* w2   = (const float*)d_in[7];
    const float* b2   = (const float*)d_in[8];
    float* out = (float*)d_out;

    char* ws = (char*)d_ws;
    size_t off = 0;
    auto alloc = [&](size_t bytes) {
        void* p = ws + off;
        off += (bytes + 255) & ~(size_t)255;
        return p;
    };
    __bf16* Apack = (__bf16*)alloc((size_t)B * S * 1024 * 2);    // 33.5 MB
    __bf16* Wpack = (__bf16*)alloc((size_t)B * NP * 1024 * 2);   // 67 MB
    __bf16* selpa = (__bf16*)alloc((size_t)B * S * TOPK * 2);    // 8.4 MB
    __bf16* PT    = (__bf16*)alloc((size_t)B * DM * TOPK * 2);   // 4.2 MB
    __bf16* Wsel  = (__bf16*)alloc((size_t)B * TOPK * 512 * 2);  // 2.1 MB
    float* scores = (float*)alloc((size_t)B * NP * 4);
    float* relacc = (float*)alloc((size_t)B * NP * 4);
    float* hacc   = (float*)alloc((size_t)B * HID * 4);
    unsigned* maskb = (unsigned*)alloc((size_t)NIN * 4);
    int* selidx   = (int*)alloc((size_t)B * TOPK * 4);
    int* selcnt   = (int*)alloc((size_t)B * 4);

    init_kernel<<<dim3((B * HID + 255) / 256), 256, 0, stream>>>(scores, relacc, hacc, maskb, selcnt);
    scatter_maskbits<<<dim3((B * KIN + 255) / 256), 256, 0, stream>>>(idx, maskb);
    pack_A<<<dim3((B * S * KIN / 4) / 256), 256, 0, stream>>>(A, Apack);
    gather_pack_w<<<dim3(NP / 4), 256, 0, stream>>>(cw, idx, Wpack);

    // scores: split-fp32 (3 segments) bf16 MFMA, 256^2 pipeline + XCD remap,
    // fused max+gelu epilogue
    mfma_gemm256<0, 3, 512, 1024, 1024, NP, NP>
        <<<dim3(S / 256, NP / 256, B), 512, 0, stream>>>(Apack, Wpack, (void*)scores);

    mlp1_part<<<dim3(HID / 64, NIN / 512), 256, 0, stream>>>(w1, maskb, hacc);
    mlp2_part<<<dim3(NP / 64, HID / 512), 256, 0, stream>>>(w2, hacc, b1, relacc);

    topk_select<<<dim3(NP / 256, B), 256, 0, stream>>>(scores, relacc, b2, selidx, selcnt);

    wsel_gather<<<dim3(TOPK, B), 256, 0, stream>>>(Wpack, selidx, Wsel);
    projT_gather<<<dim3(DM / 64, TOPK / 64, B), 256, 0, stream>>>(proj, selidx, PT);

    // selpa = gelu(A * Wsel^T) in bf16 (hi-only, 1 segment)
    mfma_gemm<1, 1, 512, 1024, 512, TOPK, TOPK>
        <<<dim3(S / 128, TOPK / 128, B), 256, 0, stream>>>(Apack, Wsel, (void*)selpa);

    // out = selpa * PT^T  (K=256, fp32 store)
    mfma_gemm<2, 1, 256, 256, 256, DM, DM>
        <<<dim3(S / 128, DM / 128, B), 256, 0, stream>>>(selpa, PT, (void*)out);
}